// Round 4
// baseline (176.403 us; speedup 1.0000x reference)
//
#include <hip/hip_runtime.h>
#include <hip/hip_bf16.h>

typedef unsigned short u16;
typedef __bf16 bf16x8 __attribute__((ext_vector_type(8)));
typedef float f32x4 __attribute__((ext_vector_type(4)));

#define GLDS16(g, l)                                                           \
  __builtin_amdgcn_global_load_lds(                                            \
      (const __attribute__((address_space(1))) unsigned int*)(g),              \
      (__attribute__((address_space(3))) unsigned int*)(l), 16, 0, 0)

static __device__ __forceinline__ u16 f2bf(float f) {
  unsigned int u = __builtin_bit_cast(unsigned int, f);
  u = (u + 0x7fffu + ((u >> 16) & 1u)) >> 16;
  return (u16)u;
}
static __device__ __forceinline__ float bf2f(u16 h) {
  return __builtin_bit_cast(float, (unsigned int)h << 16);
}

// ---------------------------------------------------------------------------
// Kernel 1 (merged): blocks [0,768): W fp32 -> Wt bf16 transpose
//                    blocks [768,4864): masked P-sum -> X bf16 [4096][768]
// ---------------------------------------------------------------------------
__global__ __launch_bounds__(256) void prep_kernel(const float* __restrict__ W,
                                                   u16* __restrict__ Wt,
                                                   const float* __restrict__ pv,
                                                   const int* __restrict__ np,
                                                   u16* __restrict__ X) {
  __shared__ float tile[32][33];
  const int bid = blockIdx.x;
  const int t = threadIdx.x;
  if (bid < 768) {  // --- wcast: 32x32 transpose tile ---
    const int n0 = (bid & 31) * 32;
    const int k0 = (bid >> 5) * 32;
#pragma unroll
    for (int i = 0; i < 4; i++) {
      int idx = t + i * 256;
      int r = idx >> 5, c = idx & 31;
      tile[r][c] = W[(size_t)(k0 + r) * 1024 + n0 + c];
    }
    __syncthreads();
#pragma unroll
    for (int i = 0; i < 4; i++) {
      int idx = t + i * 256;
      int r = idx >> 5, c = idx & 31;
      Wt[(size_t)(n0 + r) * 768 + k0 + c] = f2bf(tile[c][r]);
    }
  } else {  // --- reduce: one position per block, threads 0..191 ---
    if (t >= 192) return;
    const int pos = bid - 768;
    const int c = np[pos];
    const float4* base = (const float4*)(pv + (size_t)pos * 8 * 768);
    float4 acc = make_float4(0.f, 0.f, 0.f, 0.f);
    if (c > 0) {
      float4 v = base[t];
      for (int p = 1; p < c; p++) {
        float4 nv = base[p * 192 + t];
        acc.x += v.x; acc.y += v.y; acc.z += v.z; acc.w += v.w;
        v = nv;
      }
      acc.x += v.x; acc.y += v.y; acc.z += v.z; acc.w += v.w;
    }
    ushort4 o;
    o.x = f2bf(acc.x); o.y = f2bf(acc.y); o.z = f2bf(acc.z); o.w = f2bf(acc.w);
    ((ushort4*)(X + (size_t)pos * 768))[t] = o;
  }
}

// ---------------------------------------------------------------------------
// Kernel 2: Y[4096][1024] bf16 = X[4096][768] @ Wt[1024][768]^T
// BM=128, BN=64, BK=32; 512 blocks (2/CU); double-buffered LDS, 1 barrier/iter.
// 4 waves in 2(m)x2(n), wave tile 64x32 -> 0.75 ds_reads/MFMA (vs 1.0 at 32x32).
// ---------------------------------------------------------------------------
__global__ __launch_bounds__(256) void gemm_kernel(const u16* __restrict__ A,
                                                   const u16* __restrict__ Bt,
                                                   u16* __restrict__ Y) {
  __shared__ __attribute__((aligned(16))) u16 As[2][128 * 32];
  __shared__ __attribute__((aligned(16))) u16 Bs[2][64 * 32];
  const int tid = threadIdx.x;
  const int wave = tid >> 6;
  const int lane = tid & 63;
  const int m0 = blockIdx.y * 128;
  const int n0 = blockIdx.x * 64;

  // Staging (R1-verified): one 16B chunk = 64 lanes x 16B = 16 rows x 32k.
  // Wave w stages A-chunks 2w,2w+1 (rows [w*32,w*32+32)) and B-chunk w.
  // lane l -> row chunkbase + l/4, k-octet l%4; LDS dest = base + l*16B.
  const int lr = lane >> 2;
  const int lk = (lane & 3) * 8;
  const u16* Ag0 = A + (size_t)(m0 + wave * 32 + lr) * 768 + lk;
  const u16* Ag1 = Ag0 + 16 * 768;
  const u16* Bg = Bt + (size_t)(n0 + wave * 16 + lr) * 768 + lk;
  const int aoff0 = wave * 1024;  // u16 elements (chunk 2w @ 1024B granule /2)
  const int aoff1 = aoff0 + 512;
  const int boff = wave * 512;

  f32x4 zero = {0.f, 0.f, 0.f, 0.f};
  f32x4 acc[4][2];
#pragma unroll
  for (int i = 0; i < 4; i++)
#pragma unroll
    for (int j = 0; j < 2; j++) acc[i][j] = zero;

  const int wm = (wave >> 1) * 64;  // 0 or 64
  const int wn = (wave & 1) * 32;   // 0 or 32
  const int fm = lane & 15;
  const int fk = (lane >> 4) * 8;

  // Preload tile 0 into buffer 0
  GLDS16(Ag0, &As[0][aoff0]);
  GLDS16(Ag1, &As[0][aoff1]);
  GLDS16(Bg, &Bs[0][boff]);

#pragma unroll
  for (int i = 0; i < 24; i++) {
    __syncthreads();  // buf[i&1] staged (vmcnt drained); prev reads of buf[(i+1)&1] done
    if (i + 1 < 24) {
      GLDS16(Ag0 + (i + 1) * 32, &As[(i + 1) & 1][aoff0]);
      GLDS16(Ag1 + (i + 1) * 32, &As[(i + 1) & 1][aoff1]);
      GLDS16(Bg + (i + 1) * 32, &Bs[(i + 1) & 1][boff]);
    }
    bf16x8 af[4], bfr[2];
#pragma unroll
    for (int ii = 0; ii < 4; ii++)
      af[ii] = *(const bf16x8*)&As[i & 1][(wm + ii * 16 + fm) * 32 + fk];
#pragma unroll
    for (int j = 0; j < 2; j++)
      bfr[j] = *(const bf16x8*)&Bs[i & 1][(wn + j * 16 + fm) * 32 + fk];
#pragma unroll
    for (int ii = 0; ii < 4; ii++)
#pragma unroll
      for (int j = 0; j < 2; j++)
        acc[ii][j] = __builtin_amdgcn_mfma_f32_16x16x32_bf16(af[ii], bfr[j],
                                                             acc[ii][j], 0, 0, 0);
  }

  // C/D layout: col = lane&15, row = (lane>>4)*4 + reg
  const int cq = (lane >> 4) * 4;
#pragma unroll
  for (int ii = 0; ii < 4; ii++) {
    int rbase = m0 + wm + ii * 16 + cq;
#pragma unroll
    for (int j = 0; j < 2; j++) {
      int col = n0 + wn + j * 16 + fm;
#pragma unroll
      for (int r = 0; r < 4; r++)
        Y[(size_t)(rbase + r) * 1024 + col] = f2bf(acc[ii][j][r]);
    }
  }
}

// ---------------------------------------------------------------------------
// Kernel 3: wave-per-row LN. 4 rows/block (one per wave), grid 1024.
// pooled = (Y + cnt*b)/max(cnt,1); LayerNorm over 1024; no LDS, no barrier.
// ---------------------------------------------------------------------------
__global__ __launch_bounds__(256) void ln_kernel(const u16* __restrict__ Y,
                                                 const int* __restrict__ np,
                                                 const float* __restrict__ b,
                                                 const float* __restrict__ gamma,
                                                 const float* __restrict__ beta,
                                                 float* __restrict__ out) {
  const int t = threadIdx.x;
  const int wave = t >> 6, lane = t & 63;
  const int row = blockIdx.x * 4 + wave;
  const int c = np[row];
  const float inv = c > 0 ? 1.0f / (float)c : 0.0f;
  const float bs = c > 0 ? 1.0f : 0.0f;

  const ushort4* yrow = (const ushort4*)(Y + (size_t)row * 1024);
  float4 p[4];
  float s = 0.f, s2 = 0.f;
#pragma unroll
  for (int i = 0; i < 4; i++) {
    ushort4 yv = yrow[i * 64 + lane];
    float4 bb = ((const float4*)b)[i * 64 + lane];
    p[i].x = bf2f(yv.x) * inv + bb.x * bs;
    p[i].y = bf2f(yv.y) * inv + bb.y * bs;
    p[i].z = bf2f(yv.z) * inv + bb.z * bs;
    p[i].w = bf2f(yv.w) * inv + bb.w * bs;
    s += p[i].x + p[i].y + p[i].z + p[i].w;
    s2 += p[i].x * p[i].x + p[i].y * p[i].y + p[i].z * p[i].z + p[i].w * p[i].w;
  }
#pragma unroll
  for (int off = 32; off > 0; off >>= 1) {
    s += __shfl_down(s, off);
    s2 += __shfl_down(s2, off);
  }
  s = __shfl(s, 0);
  s2 = __shfl(s2, 0);
  const float mu = s * (1.0f / 1024.0f);
  float var = s2 * (1.0f / 1024.0f) - mu * mu;
  const float rstd = rsqrtf(var + 1e-5f);

  float4* orow = (float4*)(out + (size_t)row * 1024);
#pragma unroll
  for (int i = 0; i < 4; i++) {
    float4 g = ((const float4*)gamma)[i * 64 + lane];
    float4 be = ((const float4*)beta)[i * 64 + lane];
    float4 o;
    o.x = (p[i].x - mu) * rstd * g.x + be.x;
    o.y = (p[i].y - mu) * rstd * g.y + be.y;
    o.z = (p[i].z - mu) * rstd * g.z + be.z;
    o.w = (p[i].w - mu) * rstd * g.w + be.w;
    orow[i * 64 + lane] = o;
  }
}

// ---------------------------------------------------------------------------
extern "C" void kernel_launch(void* const* d_in, const int* in_sizes, int n_in,
                              void* d_out, int out_size, void* d_ws,
                              size_t ws_size, hipStream_t stream) {
  const float* pv = (const float*)d_in[0];     // [8,512,8,768]
  const int* np = (const int*)d_in[1];         // [8,512]
  const float* W = (const float*)d_in[2];      // [768,1024]
  const float* b = (const float*)d_in[3];      // [1024]
  const float* gamma = (const float*)d_in[4];  // [1024]
  const float* beta = (const float*)d_in[5];   // [1024]
  float* out = (float*)d_out;                  // [8,512,1024]

  char* ws = (char*)d_ws;
  u16* Wt = (u16*)ws;                          // 1,572,864 B
  u16* X = (u16*)(ws + 1572864);               // 6,291,456 B
  u16* Y = (u16*)(ws + 1572864 + 6291456);     // 8,388,608 B

  prep_kernel<<<4864, 256, 0, stream>>>(W, Wt, pv, np, X);
  gemm_kernel<<<dim3(16, 32), 256, 0, stream>>>(X, Wt, Y);
  ln_kernel<<<1024, 256, 0, stream>>>(Y, np, b, gamma, beta, out);
}